// Round 1
// baseline (411.092 us; speedup 1.0000x reference)
//
#include <hip/hip_runtime.h>

// BD field layout constants (match the reference)
#define D 256
#define MARK_AX   0
#define OP_SHL    1
#define OP_SHR    2
#define ALU_LO    16
#define ALU_HI    32
#define AX_CARRY  48
#define OUT_LO    96
#define OUT_HI    112

// One wave (64 lanes) per token. Lane i owns float4 covering elements [4i, 4i+4).
// 16 B/lane x 64 lanes = 1 KiB coalesced load + 1 KiB store per token.
__global__ __launch_bounds__(256) void alu_shift_kernel(
    const float* __restrict__ x, float* __restrict__ out, int n_tokens)
{
    const int lane = threadIdx.x & 63;
    const int wave_in_block = threadIdx.x >> 6;
    const int token = blockIdx.x * (blockDim.x >> 6) + wave_in_block;
    if (token >= n_tokens) return;

    const float4* __restrict__ xin = (const float4*)(x + (size_t)token * D);
    float4*       __restrict__ xo  = (float4*)(out + (size_t)token * D);

    float4 v = xin[lane];

    // 4-bit ">0.5" mask of this lane's elements (bit j = element 4*lane + j)
    unsigned m = (unsigned)(v.x > 0.5f)
               | ((unsigned)(v.y > 0.5f) << 1)
               | ((unsigned)(v.z > 0.5f) << 2)
               | ((unsigned)(v.w > 0.5f) << 3);

    // Lane 0 holds elements 0..3: mark (>=0.5!), shl (>0.5), shr (>0.5)
    unsigned flags = (unsigned)(v.x >= 0.5f)
                   | ((unsigned)(v.y > 0.5f) << 1)
                   | ((unsigned)(v.z > 0.5f) << 2);
    flags = __shfl(flags, 0);

    // Reassemble the three 16-bit one-hot fields.
    // ALU_LO   = elements 16..31 -> lanes 4..7
    // ALU_HI   = elements 32..47 -> lanes 8..11
    // AX_CARRY = elements 48..63 -> lanes 12..15
    unsigned mlo = __shfl(m, 4)  | (__shfl(m, 5)  << 4) | (__shfl(m, 6)  << 8) | (__shfl(m, 7)  << 12);
    unsigned mhi = __shfl(m, 8)  | (__shfl(m, 9)  << 4) | (__shfl(m, 10) << 8) | (__shfl(m, 11) << 12);
    unsigned msh = __shfl(m, 12) | (__shfl(m, 13) << 4) | (__shfl(m, 14) << 8) | (__shfl(m, 15) << 12);

    // first-hot: index of first set bit; 0 if none (matches argmax over all-false)
    int lo    = mlo ? (__ffs((int)mlo) - 1) : 0;
    int hi    = mhi ? (__ffs((int)mhi) - 1) : 0;
    int shift = msh ? (__ffs((int)msh) - 1) : 0;

    bool mark = (flags & 1u) != 0u;
    bool shl  = (flags & 2u) != 0u;
    bool shr  = (!shl) && ((flags & 4u) != 0u);
    bool active = mark && (shl || shr);

    int value = hi * 16 + lo;                       // 8-bit value
    int res = shl ? ((value << shift) & 255) : (value >> shift);
    res = active ? res : 0;

    const int tlo = OUT_LO + (res & 15);            // element 96..111
    const int thi = OUT_HI + (res >> 4);            // element 112..127 (disjoint from tlo)

    if (active) {                                   // wave-uniform branch
        const int base = lane << 2;
        v.x += (base + 0 == tlo || base + 0 == thi) ? 2.0f : 0.0f;
        v.y += (base + 1 == tlo || base + 1 == thi) ? 2.0f : 0.0f;
        v.z += (base + 2 == tlo || base + 2 == thi) ? 2.0f : 0.0f;
        v.w += (base + 3 == tlo || base + 3 == thi) ? 2.0f : 0.0f;
    }

    xo[lane] = v;
}

extern "C" void kernel_launch(void* const* d_in, const int* in_sizes, int n_in,
                              void* d_out, int out_size, void* d_ws, size_t ws_size,
                              hipStream_t stream)
{
    (void)n_in; (void)out_size; (void)d_ws; (void)ws_size;

    const float* x = (const float*)d_in[0];
    float* out = (float*)d_out;

    const int n_tokens = in_sizes[0] / D;           // B*S = 262144
    const int threads = 256;                        // 4 waves/block
    const int tokens_per_block = threads / 64;
    const int blocks = (n_tokens + tokens_per_block - 1) / tokens_per_block;

    alu_shift_kernel<<<blocks, threads, 0, stream>>>(x, out, n_tokens);
}